// Round 3
// baseline (2053.169 us; speedup 1.0000x reference)
//
#include <hip/hip_runtime.h>
#include <hip/hip_bf16.h>

#define HIDDEN 256
#define BATCH  64
#define SEQ    2048

__device__ __forceinline__ float tanh_fast(float x) {
    // tanh(x) = 1 - 2/(exp(2x)+1); exact at +-inf, ample precision vs 1.5e-2 threshold
    float e = __expf(2.0f * x);
    return 1.0f - 2.0f / (e + 1.0f);
}

// DPP cross-lane adds on the VALU pipe (NOT ds_bpermute -> keeps LDS pipe free)
#define DPP_ADD(v, CTRL)                                                        \
    (v + __int_as_float(__builtin_amdgcn_update_dpp(                            \
            0, __float_as_int(v), (CTRL), 0xF, 0xF, true)))
#define CTRL_XOR1 0xB1   // quad_perm [1,0,3,2]
#define CTRL_XOR2 0x4E   // quad_perm [2,3,0,1]
#define CTRL_HMIR 0x141  // row_half_mirror: lane ^= 7 within 8 (quad-sums uniform -> acts as xor4)

// ---------------------------------------------------------------------------
// Phase 1: x_pre[row,h] = bias[h] + sum_d embed[x[row],d] * Wx[h,d]
// 32 rows / block, 256 threads. Thread (hh=tid>>7, j2=tid&127): 16 rows x
// 2 cols {j2, j2+128}. Each LDS e-read (b128 broadcast) feeds 8 FMAs.
// ---------------------------------------------------------------------------
__global__ __launch_bounds__(256, 4)
void xpre_kernel(const int* __restrict__ x,
                 const float* __restrict__ embed,
                 const float* __restrict__ Wx,
                 const float* __restrict__ bias,
                 float* __restrict__ out) {
    const int tid = threadIdx.x;
    const int hh  = tid >> 7;        // row half: rows [16hh, 16hh+16)
    const int j2  = tid & 127;       // col pair {j2, j2+128}
    const long row0 = (long)blockIdx.x * 32;

    __shared__ int toks[32];
    __shared__ __align__(16) float e[32][HIDDEN];

    if (tid < 32) toks[tid] = x[row0 + tid];
    __syncthreads();

    #pragma unroll
    for (int r = 0; r < 32; ++r) {
        e[r][tid] = embed[(long)toks[r] * HIDDEN + tid];   // coalesced 1KB/row
    }
    __syncthreads();

    float acc0[16], acc1[16];
    const float b0 = bias[j2];
    const float b1 = bias[j2 + 128];
    #pragma unroll
    for (int r = 0; r < 16; ++r) { acc0[r] = b0; acc1[r] = b1; }

    const float* wrow0 = Wx + (size_t)j2 * HIDDEN;
    const float* wrow1 = Wx + (size_t)(j2 + 128) * HIDDEN;

    #pragma unroll 2
    for (int d0 = 0; d0 < HIDDEN; d0 += 4) {
        const float4 w0 = *(const float4*)(wrow0 + d0);
        const float4 w1 = *(const float4*)(wrow1 + d0);
        #pragma unroll
        for (int r = 0; r < 16; ++r) {
            const float4 ev = *(const float4*)&e[(hh << 4) + r][d0];  // broadcast
            float a = acc0[r];
            a = fmaf(w0.x, ev.x, a); a = fmaf(w0.y, ev.y, a);
            a = fmaf(w0.z, ev.z, a); a = fmaf(w0.w, ev.w, a);
            acc0[r] = a;
            float c = acc1[r];
            c = fmaf(w1.x, ev.x, c); c = fmaf(w1.y, ev.y, c);
            c = fmaf(w1.z, ev.z, c); c = fmaf(w1.w, ev.w, c);
            acc1[r] = c;
        }
    }

    #pragma unroll
    for (int r = 0; r < 16; ++r) {
        const long orow = (row0 + (hh << 4) + r) * HIDDEN;
        out[orow + j2]       = acc0[r];   // 256B contiguous per wave
        out[orow + j2 + 128] = acc1[r];
    }
}

// ---------------------------------------------------------------------------
// Phase 2: sequential scan. 1 block (1024 thr) per batch element.
// Thread (p = tid>>3, o = tid&7): col pair {p, p+128}, h-octant h[32o..32o+31].
// Weights: 16 named float4 (64 VGPR). h in LDS, octant stride 36 floats
// (pad kills the 8-way 128B-stride bank conflict). One barrier/step.
// 8-lane reduction via DPP adds (VALU pipe), 3 stages, 2 values.
// ---------------------------------------------------------------------------
__global__ __launch_bounds__(1024, 1)
void rnn_scan_kernel(const float* __restrict__ Wh,
                     float* __restrict__ out) {
    const int b   = blockIdx.x;
    const int tid = threadIdx.x;
    const int p   = tid >> 3;   // col pair [0,128)
    const int o   = tid & 7;    // h octant

    const float* w0p = Wh + (size_t)p * HIDDEN + (o << 5);
    const float* w1p = Wh + (size_t)(p + 128) * HIDDEN + (o << 5);
#define LDW(K) const float4 wa##K = *(const float4*)(w0p + 4*(K)); \
               const float4 wb##K = *(const float4*)(w1p + 4*(K));
    LDW(0) LDW(1) LDW(2) LDW(3) LDW(4) LDW(5) LDW(6) LDW(7)
#undef LDW

    __shared__ __align__(16) float hbuf[2][8 * 36];   // 8 octants, stride 36
    if (tid < 288) { hbuf[0][tid] = 0.0f; hbuf[1][tid] = 0.0f; }

    float* row = out + (size_t)b * SEQ * HIDDEN;
    const int col   = (o == 0) ? p : p + 128;                 // writer lanes o<2
    const int wslot = (col >> 5) * 36 + (col & 31);
    float xp = (o < 2) ? row[col] : 0.0f;                     // x_pre at t=0

    __syncthreads();

    int cur = 0;
    for (int t = 0; t < SEQ; ++t) {
        float xpn = 0.0f;
        if (o < 2 && t + 1 < SEQ) xpn = row[(size_t)(t + 1) * HIDDEN + col];

        const float* hb = hbuf[cur] + o * 36;
        float a0 = 0.f, a1 = 0.f, c0 = 0.f, c1 = 0.f;
#define STEPK(K, AC)                                                       \
        { const float4 hv = *(const float4*)(hb + 4*(K));                  \
          AC = fmaf(wa##K.x, hv.x, AC); AC = fmaf(wa##K.y, hv.y, AC);      \
          AC = fmaf(wa##K.z, hv.z, AC); AC = fmaf(wa##K.w, hv.w, AC);      \
          float cc = (&c0)[&AC - &a0];                                     \
          (void)cc; }
        // (manual expansion below instead of pointer tricks)
#undef STEPK
#define STEP2(K, A, C)                                                     \
        { const float4 hv = *(const float4*)(hb + 4*(K));                  \
          A = fmaf(wa##K.x, hv.x, A); A = fmaf(wa##K.y, hv.y, A);          \
          A = fmaf(wa##K.z, hv.z, A); A = fmaf(wa##K.w, hv.w, A);          \
          C = fmaf(wb##K.x, hv.x, C); C = fmaf(wb##K.y, hv.y, C);          \
          C = fmaf(wb##K.z, hv.z, C); C = fmaf(wb##K.w, hv.w, C); }
        STEP2(0, a0, c0) STEP2(1, a1, c1) STEP2(2, a0, c0) STEP2(3, a1, c1)
        STEP2(4, a0, c0) STEP2(5, a1, c1) STEP2(6, a0, c0) STEP2(7, a1, c1)
#undef STEP2
        float as = a0 + a1;
        float cs = c0 + c1;
        // 8-lane butterfly on VALU pipe
        as = DPP_ADD(as, CTRL_XOR1);  cs = DPP_ADD(cs, CTRL_XOR1);
        as = DPP_ADD(as, CTRL_XOR2);  cs = DPP_ADD(cs, CTRL_XOR2);
        as = DPP_ADD(as, CTRL_HMIR);  cs = DPP_ADD(cs, CTRL_HMIR);

        if (o < 2) {
            const float s = (o == 0) ? as : cs;
            const float h = tanh_fast(xp + s);
            row[(size_t)t * HIDDEN + col] = h;   // overwrite consumed x_pre
            hbuf[cur ^ 1][wslot] = h;
        }
        __syncthreads();                          // one barrier per step
        cur ^= 1;
        xp = xpn;
    }
}

extern "C" void kernel_launch(void* const* d_in, const int* in_sizes, int n_in,
                              void* d_out, int out_size, void* d_ws, size_t ws_size,
                              hipStream_t stream) {
    const int*   x     = (const int*)d_in[0];
    const float* embed = (const float*)d_in[1];
    const float* Wx    = (const float*)d_in[2];
    const float* Wxb   = (const float*)d_in[3];
    const float* Wh    = (const float*)d_in[4];
    float* out = (float*)d_out;

    const int nrows = BATCH * SEQ;                  // 131072, 32 rows/block
    xpre_kernel<<<nrows / 32, 256, 0, stream>>>(x, embed, Wx, Wxb, out);

    rnn_scan_kernel<<<BATCH, 1024, 0, stream>>>(Wh, out);
}

// Round 4
// 1998.562 us; speedup vs baseline: 1.0273x; 1.0273x over previous
//
#include <hip/hip_runtime.h>
#include <hip/hip_bf16.h>

#define HIDDEN 256
#define BATCH  64
#define SEQ    2048

typedef float v2f __attribute__((ext_vector_type(2)));

__device__ __forceinline__ float tanh_fast(float x) {
    float e = __expf(2.0f * x);
    return 1.0f - 2.0f / (e + 1.0f);
}

// DPP cross-lane adds on the VALU pipe (keeps LDS pipe free)
#define DPP_ADD(v, CTRL)                                                        \
    (v + __int_as_float(__builtin_amdgcn_update_dpp(                            \
            0, __float_as_int(v), (CTRL), 0xF, 0xF, true)))
#define CTRL_XOR1 0xB1   // quad_perm [1,0,3,2]
#define CTRL_XOR2 0x4E   // quad_perm [2,3,0,1]
#define CTRL_HMIR 0x141  // row_half_mirror (acts as xor4 once quads are uniform)

// LDS-only barrier: sync LDS handoff WITHOUT draining vmcnt (global ops stay
// in flight across the barrier -- removes L3/HBM latency from the step path).
#define BAR_LDS() do {                                                          \
    asm volatile("s_waitcnt lgkmcnt(0)\n\ts_barrier" ::: "memory");             \
    __builtin_amdgcn_sched_barrier(0);                                          \
} while (0)

// ---------------------------------------------------------------------------
// Phase 1: x_pre[row,h] = bias[h] + sum_d embed[x[row],d] * Wx[h,d]
// 32 rows/block, 256 threads. Thread (rg=tid>>6, j=tid&63): 8 rows x 4 cols
// {j, j+64, j+128, j+192}. Each broadcast e-read feeds 32 MACs (16 pk_fma).
// ---------------------------------------------------------------------------
__global__ __launch_bounds__(256, 3)
void xpre_kernel(const int* __restrict__ x,
                 const float* __restrict__ embed,
                 const float* __restrict__ Wx,
                 const float* __restrict__ bias,
                 float* __restrict__ out) {
    const int tid = threadIdx.x;
    const int j   = tid & 63;          // base column
    const int rg  = tid >> 6;          // row group: rows [8rg, 8rg+8)
    const long row0 = (long)blockIdx.x * 32;

    __shared__ int toks[32];
    __shared__ __align__(16) float e[32][HIDDEN];

    if (tid < 32) toks[tid] = x[row0 + tid];
    __syncthreads();

    #pragma unroll
    for (int r = 0; r < 32; ++r)
        e[r][tid] = embed[(long)toks[r] * HIDDEN + tid];   // coalesced 1KB/row
    __syncthreads();

    const float* w0 = Wx + (size_t)(j      ) * HIDDEN;
    const float* w1 = Wx + (size_t)(j +  64) * HIDDEN;
    const float* w2 = Wx + (size_t)(j + 128) * HIDDEN;
    const float* w3 = Wx + (size_t)(j + 192) * HIDDEN;

    v2f acc[4][8];
    #pragma unroll
    for (int c = 0; c < 4; ++c)
        #pragma unroll
        for (int r = 0; r < 8; ++r) acc[c][r] = (v2f){0.f, 0.f};

    const int rbase = rg << 3;

    #pragma unroll 2
    for (int d0 = 0; d0 < HIDDEN; d0 += 4) {
        const float4 wv0 = *(const float4*)(w0 + d0);
        const float4 wv1 = *(const float4*)(w1 + d0);
        const float4 wv2 = *(const float4*)(w2 + d0);
        const float4 wv3 = *(const float4*)(w3 + d0);
        const v2f w0a = {wv0.x, wv0.y}, w0b = {wv0.z, wv0.w};
        const v2f w1a = {wv1.x, wv1.y}, w1b = {wv1.z, wv1.w};
        const v2f w2a = {wv2.x, wv2.y}, w2b = {wv2.z, wv2.w};
        const v2f w3a = {wv3.x, wv3.y}, w3b = {wv3.z, wv3.w};
        #pragma unroll
        for (int r = 0; r < 8; ++r) {
            const float4 ev = *(const float4*)&e[rbase + r][d0];  // broadcast
            const v2f e0 = {ev.x, ev.y}, e1 = {ev.z, ev.w};
            acc[0][r] = __builtin_elementwise_fma(w0a, e0, acc[0][r]);
            acc[0][r] = __builtin_elementwise_fma(w0b, e1, acc[0][r]);
            acc[1][r] = __builtin_elementwise_fma(w1a, e0, acc[1][r]);
            acc[1][r] = __builtin_elementwise_fma(w1b, e1, acc[1][r]);
            acc[2][r] = __builtin_elementwise_fma(w2a, e0, acc[2][r]);
            acc[2][r] = __builtin_elementwise_fma(w2b, e1, acc[2][r]);
            acc[3][r] = __builtin_elementwise_fma(w3a, e0, acc[3][r]);
            acc[3][r] = __builtin_elementwise_fma(w3b, e1, acc[3][r]);
        }
    }

    const float b0 = bias[j], b1 = bias[j + 64], b2 = bias[j + 128], b3 = bias[j + 192];
    #pragma unroll
    for (int r = 0; r < 8; ++r) {
        const size_t orow = (size_t)(row0 + rbase + r) * HIDDEN;
        out[orow + j]       = b0 + acc[0][r].x + acc[0][r].y;
        out[orow + j + 64]  = b1 + acc[1][r].x + acc[1][r].y;
        out[orow + j + 128] = b2 + acc[2][r].x + acc[2][r].y;
        out[orow + j + 192] = b3 + acc[3][r].x + acc[3][r].y;
    }
}

// ---------------------------------------------------------------------------
// Phase 2: sequential scan. 1 block (1024 thr) per batch element.
// Thread (p=tid>>3, o=tid&7): col pair {p, p+128}, h-octant h[32o..32o+31].
// Weights: 32 named v2f (64 VGPR). MACs via v_pk_fma_f32 (h packed in pairs).
// h in LDS (octant stride 36 kills bank conflicts), double-buffered.
// Per-step sync = LDS-only barrier (global load/store stay in flight).
// ---------------------------------------------------------------------------
__global__ __launch_bounds__(1024, 1)
void rnn_scan_kernel(const float* __restrict__ Wh,
                     float* __restrict__ out) {
    const int b   = blockIdx.x;
    const int tid = threadIdx.x;
    const int p   = tid >> 3;   // col pair [0,128)
    const int o   = tid & 7;    // h octant

    const float* w0p = Wh + (size_t)p * HIDDEN + (o << 5);
    const float* w1p = Wh + (size_t)(p + 128) * HIDDEN + (o << 5);
#define LDW(K)                                                                  \
    const float4 fa##K = *(const float4*)(w0p + 4*(K));                         \
    const float4 fb##K = *(const float4*)(w1p + 4*(K));                         \
    const v2f wa##K##0 = {fa##K.x, fa##K.y}; const v2f wa##K##1 = {fa##K.z, fa##K.w}; \
    const v2f wb##K##0 = {fb##K.x, fb##K.y}; const v2f wb##K##1 = {fb##K.z, fb##K.w};
    LDW(0) LDW(1) LDW(2) LDW(3) LDW(4) LDW(5) LDW(6) LDW(7)
#undef LDW

    __shared__ __align__(16) float hbuf[2][8 * 36];   // 8 octants, stride 36
    if (tid < 288) { hbuf[0][tid] = 0.0f; hbuf[1][tid] = 0.0f; }

    float* row = out + (size_t)b * SEQ * HIDDEN;
    const int col   = (o == 0) ? p : p + 128;                 // writer lanes o<2
    const int wslot = (col >> 5) * 36 + (col & 31);
    float xp = (o < 2) ? row[col] : 0.0f;                     // x_pre at t=0

    __syncthreads();   // one-time full barrier (also drains weight loads)

    float* hcur = hbuf[0];
    float* hnxt = hbuf[1];

    for (int t = 0; t < SEQ; ++t) {
        float xpn = 0.0f;
        if (o < 2 && t + 1 < SEQ) xpn = row[(size_t)(t + 1) * HIDDEN + col];

        const float* hb = hcur + o * 36;
        v2f aA = {0.f,0.f}, aB = {0.f,0.f}, cA = {0.f,0.f}, cB = {0.f,0.f};
#define STEP(K, A, C)                                                           \
        { const float4 hv = *(const float4*)(hb + 4*(K));                       \
          const v2f h0 = {hv.x, hv.y}, h1 = {hv.z, hv.w};                       \
          A = __builtin_elementwise_fma(wa##K##0, h0, A);                       \
          A = __builtin_elementwise_fma(wa##K##1, h1, A);                       \
          C = __builtin_elementwise_fma(wb##K##0, h0, C);                       \
          C = __builtin_elementwise_fma(wb##K##1, h1, C); }
        STEP(0, aA, cA) STEP(1, aB, cB) STEP(2, aA, cA) STEP(3, aB, cB)
        STEP(4, aA, cA) STEP(5, aB, cB) STEP(6, aA, cA) STEP(7, aB, cB)
#undef STEP
        const v2f sa = aA + aB;
        const v2f sc = cA + cB;
        float as = sa.x + sa.y;
        float cs = sc.x + sc.y;
        // 8-lane butterfly on the VALU pipe
        as = DPP_ADD(as, CTRL_XOR1);  cs = DPP_ADD(cs, CTRL_XOR1);
        as = DPP_ADD(as, CTRL_XOR2);  cs = DPP_ADD(cs, CTRL_XOR2);
        as = DPP_ADD(as, CTRL_HMIR);  cs = DPP_ADD(cs, CTRL_HMIR);

        if (o < 2) {
            const float s = (o == 0) ? as : cs;
            const float h = tanh_fast(xp + s);
            row[(size_t)t * HIDDEN + col] = h;   // fire-and-forget store
            hnxt[wslot] = h;                     // LDS handoff
        }
        BAR_LDS();                               // lgkmcnt-only barrier
        float* tmp = hcur; hcur = hnxt; hnxt = tmp;
        xp = xpn;
    }
}

extern "C" void kernel_launch(void* const* d_in, const int* in_sizes, int n_in,
                              void* d_out, int out_size, void* d_ws, size_t ws_size,
                              hipStream_t stream) {
    const int*   x     = (const int*)d_in[0];
    const float* embed = (const float*)d_in[1];
    const float* Wx    = (const float*)d_in[2];
    const float* Wxb   = (const float*)d_in[3];
    const float* Wh    = (const float*)d_in[4];
    float* out = (float*)d_out;

    const int nrows = BATCH * SEQ;                  // 131072, 32 rows/block
    xpre_kernel<<<nrows / 32, 256, 0, stream>>>(x, embed, Wx, Wxb, out);

    rnn_scan_kernel<<<BATCH, 1024, 0, stream>>>(Wh, out);
}

// Round 6
// 1729.189 us; speedup vs baseline: 1.1874x; 1.1558x over previous
//
#include <hip/hip_runtime.h>
#include <hip/hip_bf16.h>

#define HIDDEN 256
#define BATCH  64
#define SEQ    2048

typedef float v2f __attribute__((ext_vector_type(2)));

__device__ __forceinline__ float tanh_fast(float x) {
    float e = __expf(2.0f * x);
    return 1.0f - 2.0f / (e + 1.0f);
}

// DPP cross-lane adds on the VALU pipe (keeps the CU-shared LDS pipe free)
#define DPP_ADD(v, CTRL)                                                        \
    (v + __int_as_float(__builtin_amdgcn_update_dpp(                            \
            0, __float_as_int(v), (CTRL), 0xF, 0xF, true)))
#define CTRL_XOR1 0xB1   // quad_perm [1,0,3,2]            = xor1
#define CTRL_XOR2 0x4E   // quad_perm [2,3,0,1]            = xor2
#define CTRL_HMIR 0x141  // row_half_mirror (l^7) == xor4 after quads uniform
#define CTRL_MIR  0x140  // row_mirror      (l^15) == xor8 after 8-uniform

// LDS-only barrier: sync LDS handoff WITHOUT draining vmcnt (global prefetch
// loads / stores stay in flight across the barrier).
#define BAR_LDS() do {                                                          \
    asm volatile("s_waitcnt lgkmcnt(0)\n\ts_barrier" ::: "memory");             \
    __builtin_amdgcn_sched_barrier(0);                                          \
} while (0)

// ---------------------------------------------------------------------------
// Phase 1: x_pre[row,h] = bias[h] + sum_d embed[x[row],d] * Wx[h,d]
// (R2/R3 structure: 32 rows/block, 256 thr, 16 rows x 2 cols per thread)
// ---------------------------------------------------------------------------
__global__ __launch_bounds__(256, 4)
void xpre_kernel(const int* __restrict__ x,
                 const float* __restrict__ embed,
                 const float* __restrict__ Wx,
                 const float* __restrict__ bias,
                 float* __restrict__ out) {
    const int tid = threadIdx.x;
    const int hh  = tid >> 7;        // row half: rows [16hh, 16hh+16)
    const int j2  = tid & 127;       // col pair {j2, j2+128}
    const long row0 = (long)blockIdx.x * 32;

    __shared__ int toks[32];
    __shared__ __align__(16) float e[32][HIDDEN];

    if (tid < 32) toks[tid] = x[row0 + tid];
    __syncthreads();

    #pragma unroll
    for (int r = 0; r < 32; ++r) {
        e[r][tid] = embed[(long)toks[r] * HIDDEN + tid];   // coalesced 1KB/row
    }
    __syncthreads();

    float acc0[16], acc1[16];
    const float b0 = bias[j2];
    const float b1 = bias[j2 + 128];
    #pragma unroll
    for (int r = 0; r < 16; ++r) { acc0[r] = b0; acc1[r] = b1; }

    const float* wrow0 = Wx + (size_t)j2 * HIDDEN;
    const float* wrow1 = Wx + (size_t)(j2 + 128) * HIDDEN;

    #pragma unroll 2
    for (int d0 = 0; d0 < HIDDEN; d0 += 4) {
        const float4 w0 = *(const float4*)(wrow0 + d0);
        const float4 w1 = *(const float4*)(wrow1 + d0);
        #pragma unroll
        for (int r = 0; r < 16; ++r) {
            const float4 ev = *(const float4*)&e[(hh << 4) + r][d0];  // broadcast
            float a = acc0[r];
            a = fmaf(w0.x, ev.x, a); a = fmaf(w0.y, ev.y, a);
            a = fmaf(w0.z, ev.z, a); a = fmaf(w0.w, ev.w, a);
            acc0[r] = a;
            float c = acc1[r];
            c = fmaf(w1.x, ev.x, c); c = fmaf(w1.y, ev.y, c);
            c = fmaf(w1.z, ev.z, c); c = fmaf(w1.w, ev.w, c);
            acc1[r] = c;
        }
    }

    #pragma unroll
    for (int r = 0; r < 16; ++r) {
        const long orow = (row0 + (hh << 4) + r) * HIDDEN;
        out[orow + j2]       = acc0[r];
        out[orow + j2 + 128] = acc1[r];
    }
}

// ---------------------------------------------------------------------------
// Phase 2: sequential scan. 1 block (512 thr, 8 waves) per batch element.
// Thread (o = tid&15, pc = tid>>4): 8 columns {pc+32k}, h-slice h[16o..16o+15].
// Weights: 64 named v2f = 128 VGPR. Per step: 4 ds_read_b128 (padded layout),
// 64 pk_fma, 16-lane DPP butterfly (VALU pipe) -> every lane has all 8 sums.
// Writer lanes (o<8) select sum o, tanh, store to global + LDS.
// LDS traffic: 32 wave-reads/CU/step (was 128). BAR_LDS per step.
// ---------------------------------------------------------------------------
__global__ __launch_bounds__(512, 2)
void rnn_scan_kernel(const float* __restrict__ Wh,
                     float* __restrict__ out) {
    const int b   = blockIdx.x;
    const int tid = threadIdx.x;
    const int o   = tid & 15;    // h-slice index
    const int pc  = tid >> 4;    // column base [0,32)

    // 8 columns x 16 weights = 32 float4 -> 64 named v2f (128 VGPR)
#define LDWCOL(K)                                                               \
    const float* wp##K = Wh + (size_t)(pc + 32*(K)) * HIDDEN + (o << 4);        \
    const float4 f##K##a = *(const float4*)(wp##K);                             \
    const float4 f##K##b = *(const float4*)(wp##K + 4);                         \
    const float4 f##K##c = *(const float4*)(wp##K + 8);                         \
    const float4 f##K##d = *(const float4*)(wp##K + 12);                        \
    const v2f w##K##0 = {f##K##a.x, f##K##a.y}; const v2f w##K##1 = {f##K##a.z, f##K##a.w}; \
    const v2f w##K##2 = {f##K##b.x, f##K##b.y}; const v2f w##K##3 = {f##K##b.z, f##K##b.w}; \
    const v2f w##K##4 = {f##K##c.x, f##K##c.y}; const v2f w##K##5 = {f##K##c.z, f##K##c.w}; \
    const v2f w##K##6 = {f##K##d.x, f##K##d.y}; const v2f w##K##7 = {f##K##d.z, f##K##d.w};
    LDWCOL(0) LDWCOL(1) LDWCOL(2) LDWCOL(3)
    LDWCOL(4) LDWCOL(5) LDWCOL(6) LDWCOL(7)
#undef LDWCOL

    // h layout: float f stored at slot f + 4*(f>>4)  (4-float pad per 16)
    __shared__ __align__(16) float hbuf[2][320];
    if (tid < 320) { hbuf[0][tid] = 0.0f; hbuf[1][tid] = 0.0f; }

    float* row = out + (size_t)b * SEQ * HIDDEN;
    const int col   = pc + (o << 5);            // writer (o<8) column
    const int wslot = col + 4 * (col >> 4);     // padded LDS slot
    float xp = (o < 8) ? row[col] : 0.0f;       // x_pre at t=0

    __syncthreads();

    float* hcur = hbuf[0];
    float* hnxt = hbuf[1];

    for (int t = 0; t < SEQ; ++t) {
        float xpn = 0.0f;
        if (o < 8 && t + 1 < SEQ) xpn = row[(size_t)(t + 1) * HIDDEN + col];

        // read my 16-float h slice (4 x b128, <=2-way bank alias = free)
        const float* hb = hcur + 20 * o;
        const float4 hva = *(const float4*)(hb);
        const float4 hvb = *(const float4*)(hb + 4);
        const float4 hvc = *(const float4*)(hb + 8);
        const float4 hvd = *(const float4*)(hb + 12);
        const v2f h0 = {hva.x, hva.y}, h1 = {hva.z, hva.w};
        const v2f h2 = {hvb.x, hvb.y}, h3 = {hvb.z, hvb.w};
        const v2f h4 = {hvc.x, hvc.y}, h5 = {hvc.z, hvc.w};
        const v2f h6 = {hvd.x, hvd.y}, h7 = {hvd.z, hvd.w};

        // 8 columns x 8 pk_fma
#define MACCOL(K, S)                                                            \
        {   v2f a = {0.f, 0.f}, c = {0.f, 0.f};                                 \
            a = __builtin_elementwise_fma(w##K##0, h0, a);                      \
            c = __builtin_elementwise_fma(w##K##1, h1, c);                      \
            a = __builtin_elementwise_fma(w##K##2, h2, a);                      \
            c = __builtin_elementwise_fma(w##K##3, h3, c);                      \
            a = __builtin_elementwise_fma(w##K##4, h4, a);                      \
            c = __builtin_elementwise_fma(w##K##5, h5, c);                      \
            a = __builtin_elementwise_fma(w##K##6, h6, a);                      \
            c = __builtin_elementwise_fma(w##K##7, h7, c);                      \
            const v2f sv = a + c;                                               \
            S = sv.x + sv.y; }
        float s0, s1, s2, s3, s4, s5, s6, s7;
        MACCOL(0, s0) MACCOL(1, s1) MACCOL(2, s2) MACCOL(3, s3)
        MACCOL(4, s4) MACCOL(5, s5) MACCOL(6, s6) MACCOL(7, s7)
#undef MACCOL

        // 16-lane butterfly on the VALU pipe: xor1, xor2, ~xor4, ~xor8
#define RED4(S)                                                                 \
        S = DPP_ADD(S, CTRL_XOR1);                                              \
        S = DPP_ADD(S, CTRL_XOR2);                                              \
        S = DPP_ADD(S, CTRL_HMIR);                                              \
        S = DPP_ADD(S, CTRL_MIR);
        RED4(s0) RED4(s1) RED4(s2) RED4(s3)
        RED4(s4) RED4(s5) RED4(s6) RED4(s7)
#undef RED4

        // select sum (o&7) via cndmask tree, tanh (all lanes; writers store)
        const int k = o & 7;
        const float t01 = (k & 1) ? s1 : s0;
        const float t23 = (k & 1) ? s3 : s2;
        const float t45 = (k & 1) ? s5 : s4;
        const float t67 = (k & 1) ? s7 : s6;
        const float u0  = (k & 2) ? t23 : t01;
        const float u1  = (k & 2) ? t67 : t45;
        const float s   = (k & 4) ? u1 : u0;

        const float h = tanh_fast(xp + s);

        if (o < 8) {
            row[(size_t)t * HIDDEN + col] = h;   // fire-and-forget store
            hnxt[wslot] = h;                     // padded LDS handoff
        }
        BAR_LDS();                               // lgkmcnt-only barrier
        float* tmp = hcur; hcur = hnxt; hnxt = tmp;
        xp = xpn;
    }
}

extern "C" void kernel_launch(void* const* d_in, const int* in_sizes, int n_in,
                              void* d_out, int out_size, void* d_ws, size_t ws_size,
                              hipStream_t stream) {
    const int*   x     = (const int*)d_in[0];
    const float* embed = (const float*)d_in[1];
    const float* Wx    = (const float*)d_in[2];
    const float* Wxb   = (const float*)d_in[3];
    const float* Wh    = (const float*)d_in[4];
    float* out = (float*)d_out;

    const int nrows = BATCH * SEQ;                  // 131072, 32 rows/block
    xpre_kernel<<<nrows / 32, 256, 0, stream>>>(x, embed, Wx, Wxb, out);

    rnn_scan_kernel<<<BATCH, 512, 0, stream>>>(Wh, out);
}